// Round 11
// baseline (61.701 us; speedup 1.0000x reference)
//
#include <hip/hip_runtime.h>
#include <math.h>

// DTLN part-2, 3 kernels (2 boundaries + 1 in-kernel flag).
// K1: enc (256 blk) + ph1/ph2 recurrent partials (64 blk) + ws init.
// K2: LN (cheap redundant) + z1 gate-rows -> h1,c1 (128 blk).
// K3 (k_tail, 264 blk): blocks 0..7 = z2 (16 units each) -> gates2 -> h2 ->
//     rank-16 dense scatter into macc (8 adds/line; per-line winner via
//     same-line counter finalizes est_g[r]); 8 block-level counter RMWs,
//     last sets flag. Blocks 8..263 = dec rows: prefetch dec_W into regs
//     (overlaps z2 phase), poll flag, read est_g (1KB), dot, store.

#define FRAME 1024
#define ENC 256
#define HID 128
#define MSTRIDE 32   // floats per macc line (128B)
#define NZ2 8        // z2 producer blocks
#define UPB 16       // units per z2 block
#define SCOPE __HIP_MEMORY_SCOPE_AGENT

__device__ __forceinline__ float sigmoidf_(float x) { return 1.0f / (1.0f + __expf(-x)); }
__device__ __forceinline__ float tanhf_(float x) { return 2.0f * sigmoidf_(2.0f * x) - 1.0f; }

__device__ __forceinline__ float wred(float v) {
#pragma unroll
    for (int o = 32; o > 0; o >>= 1) v += __shfl_xor(v, o);
    return v;  // all lanes
}

// ---- K1: enc rows (256 blk) + ph1/ph2 partials (64 blk) + ws init ----
__global__ __launch_bounds__(256) void k_enc(
    const float* __restrict__ enc_W, const float* __restrict__ y1,
    const float* __restrict__ Whh1, const float* __restrict__ bih1,
    const float* __restrict__ bhh1, const float* __restrict__ h1_in,
    const float* __restrict__ Whh2, const float* __restrict__ bih2,
    const float* __restrict__ bhh2, const float* __restrict__ h2_in,
    float* __restrict__ enc_g, float* __restrict__ ph1,
    float* __restrict__ ph2, float* __restrict__ macc,
    unsigned* __restrict__ ctr, unsigned* __restrict__ flag) {
    const int t = threadIdx.x, lane = t & 63, w = t >> 6, bid = blockIdx.x;
    if (bid < 256) {
        const float4 a = reinterpret_cast<const float4*>(enc_W + bid * FRAME)[t];
        const float4 b = reinterpret_cast<const float4*>(y1)[t];
        float p = a.x * b.x + a.y * b.y + a.z * b.z + a.w * b.w;
        p = wred(p);
        __shared__ float red[4];
        if (lane == 0) red[w] = p;
        __syncthreads();
        if (t == 0) enc_g[bid] = red[0] + red[1] + red[2] + red[3];
    } else {
        const bool is1 = bid < 288;
        const int pb = is1 ? bid - 256 : bid - 288;   // 32 blocks each side
        const float* Whh = is1 ? Whh1 : Whh2;
        const float* bi  = is1 ? bih1 : bih2;
        const float* bh  = is1 ? bhh1 : bhh2;
        const float* hin = is1 ? h1_in : h2_in;
        float* dst       = is1 ? ph1 : ph2;
        const float2 hv = reinterpret_cast<const float2*>(hin)[lane];
#pragma unroll
        for (int j = 0; j < 4; ++j) {
            const int r = pb * 16 + w * 4 + j;        // 16 rows/block, 512 total
            const float2 a = reinterpret_cast<const float2*>(Whh + r * HID)[lane];
            float p = a.x * hv.x + a.y * hv.y;
            p = wred(p);
            if (lane == 0) dst[r] = p + bi[r] + bh[r];
        }
        if (!is1) {
            if (t < 8) {
                const int s = (pb * 8 + t) * MSTRIDE;
                macc[s] = 0.0f;                       // accumulator
                ((unsigned*)macc)[s + 1] = 0u;        // per-line contributor count
            }
            if (pb == 0 && t == 8) *ctr = 0u;
            if (pb == 0 && t == 9) *flag = 0u;
        }
    }
}

// ---- K2: LN (cheap redundant) + z1 gate-rows of unit b -> h1,c1. 128 blk ----
__global__ __launch_bounds__(256) void k_z1(
    const float* __restrict__ enc_g, const float* __restrict__ gamma,
    const float* __restrict__ beta, const float* __restrict__ Wih1,
    const float* __restrict__ ph1, const float* __restrict__ c1_in,
    float* __restrict__ h1_g, float* __restrict__ out) {
    const int t = threadIdx.x, lane = t & 63, w = t >> 6, b = blockIdx.x;
    __shared__ __align__(16) float encN[ENC];
    __shared__ float red[8];
    __shared__ float zsh[4];

    const int r = b + HID * w;  // gate w of unit b
    const float4 wa = reinterpret_cast<const float4*>(Wih1 + r * ENC)[lane];
    const float ph = ph1[r];

    const float e = enc_g[t];
    const float s1 = wred(e);
    const float s2 = wred(e * e);
    if (lane == 0) { red[w] = s1; red[4 + w] = s2; }
    __syncthreads();
    const float mean = (red[0] + red[1] + red[2] + red[3]) * (1.f / ENC);
    const float var  = (red[4] + red[5] + red[6] + red[7]) * (1.f / ENC) - mean * mean;
    const float inv  = rsqrtf(var + 1e-7f);
    encN[t] = (e - mean) * inv * gamma[t] + beta[t];
    __syncthreads();

    const float4 xa = reinterpret_cast<const float4*>(encN)[lane];
    float p = wa.x * xa.x + wa.y * xa.y + wa.z * xa.z + wa.w * xa.w;
    p = wred(p);
    if (lane == 0) zsh[w] = p + ph;
    __syncthreads();
    if (t == 0) {
        const float i = sigmoidf_(zsh[0]);
        const float f = sigmoidf_(zsh[1]);
        const float g = tanhf_(zsh[2]);
        const float o = sigmoidf_(zsh[3]);
        const float c = f * c1_in[b] + i * g;
        const float h = o * tanhf_(c);
        h1_g[b] = h;
        out[FRAME + b] = h;
        out[FRAME + HID + b] = c;
    }
}

// ---- K3: z2 producers (8 blk) + dec consumers (256 blk), flag-coupled ----
__global__ __launch_bounds__(256) void k_tail(
    const float* __restrict__ h1_g, const float* __restrict__ Wih2,
    const float* __restrict__ ph2, const float* __restrict__ c2_in,
    const float* __restrict__ dense_W, const float* __restrict__ dense_b,
    const float* __restrict__ enc_g, const float* __restrict__ dec_W,
    float* __restrict__ macc, float* __restrict__ est_g,
    unsigned* __restrict__ ctr, unsigned* __restrict__ flag,
    float* __restrict__ out) {
    const int t = threadIdx.x, lane = t & 63, w = t >> 6, bid = blockIdx.x;

    if (bid < NZ2) {
        // ---------- producer: z2 rows for units [ub, ub+16) ----------
        __shared__ __align__(16) float hA[HID];
        __shared__ float zsh[4][UPB];
        __shared__ float h2sh[UPB];
        const int ub = bid * UPB;
        const int sub = lane >> 2, q = lane & 3;

        // prefetch (input-only): wave w = gate w; row r = (ub+sub) + 128*w
        const int r = (ub + sub) + HID * w;
        float4 wa[8];
        const float4* W4 = reinterpret_cast<const float4*>(Wih2 + r * HID) + q * 8;
#pragma unroll
        for (int i = 0; i < 8; ++i) wa[i] = W4[i];
        const float phv = ph2[r];
        float4 dcol[4];
        const float4* D4 = reinterpret_cast<const float4*>(dense_W + t * HID + ub);
#pragma unroll
        for (int i = 0; i < 4; ++i) dcol[i] = D4[i];
        const float dbv = dense_b[t];
        const float ebv = enc_g[t];

        if (t < HID) hA[t] = h1_g[t];
        __syncthreads();
        const float4* x4 = reinterpret_cast<const float4*>(hA) + q * 8;
        float4 acc = {0.f, 0.f, 0.f, 0.f};
#pragma unroll
        for (int i = 0; i < 8; ++i) {
            const float4 xv = x4[i];
            acc.x += wa[i].x * xv.x; acc.y += wa[i].y * xv.y;
            acc.z += wa[i].z * xv.z; acc.w += wa[i].w * xv.w;
        }
        float p = acc.x + acc.y + acc.z + acc.w;
        p += __shfl_xor(p, 1); p += __shfl_xor(p, 2);
        if (q == 0) zsh[w][sub] = p + phv;
        __syncthreads();
        if (t < UPB) {
            const int u = ub + t;
            const float i_ = sigmoidf_(zsh[0][t]);
            const float f_ = sigmoidf_(zsh[1][t]);
            const float g_ = tanhf_(zsh[2][t]);
            const float o_ = sigmoidf_(zsh[3][t]);
            const float c = f_ * c2_in[u] + i_ * g_;
            const float h = o_ * tanhf_(c);
            h2sh[t] = h;
            out[FRAME + 2 * HID + u] = h;
            out[FRAME + 3 * HID + u] = c;
        }
        __syncthreads();
        // rank-16 contribution to mask row t; winner (8th contributor) finalizes est
        float contrib = 0.f;
#pragma unroll
        for (int i = 0; i < 4; ++i) {
            contrib += dcol[i].x * h2sh[i * 4 + 0] + dcol[i].y * h2sh[i * 4 + 1]
                     + dcol[i].z * h2sh[i * 4 + 2] + dcol[i].w * h2sh[i * 4 + 3];
        }
        const float oldv = atomicAdd(&macc[t * MSTRIDE], contrib);
        unsigned* mct = (unsigned*)&macc[t * MSTRIDE + 1];
        const unsigned oc = __hip_atomic_fetch_add(mct, 1u, __ATOMIC_ACQ_REL, SCOPE);
        if (oc == NZ2 - 1u) {
            // my add was last; oldv holds the sum of the other 7 (their macc adds
            // are ordered-before their mct release, acquired by my mct RMW)
            const float mfin = __hip_atomic_load(&macc[t * MSTRIDE], __ATOMIC_RELAXED, SCOPE);
            (void)oldv;
            const float e_ = sigmoidf_(mfin + dbv) * ebv;
            __hip_atomic_store(&est_g[t], e_, __ATOMIC_RELAXED, SCOPE);
        }
        __syncthreads();
        if (t == 0) {
            const unsigned ob = __hip_atomic_fetch_add(ctr, 1u, __ATOMIC_ACQ_REL, SCOPE);
            if (ob == NZ2 - 1u)
                __hip_atomic_store(flag, 1u, __ATOMIC_RELEASE, SCOPE);
        }
    } else {
        // ---------- consumer: 4 dec rows; dec_W prefetched during z2 phase ----------
        __shared__ __align__(16) float es[ENC];
        const int r = (bid - NZ2) * 4 + w;
        const float4 a = reinterpret_cast<const float4*>(dec_W + r * ENC)[lane];
        if (t == 0) {
            while (__hip_atomic_load(flag, __ATOMIC_ACQUIRE, SCOPE) == 0u)
                __builtin_amdgcn_s_sleep(2);
        }
        __syncthreads();
        es[t] = __hip_atomic_load(&est_g[t], __ATOMIC_RELAXED, SCOPE);
        __syncthreads();
        const float4 bb = reinterpret_cast<const float4*>(es)[lane];
        float p = a.x * bb.x + a.y * bb.y + a.z * bb.z + a.w * bb.w;
        p = wred(p);
        if (lane == 0) out[r] = p;
    }
}

extern "C" void kernel_launch(void* const* d_in, const int* in_sizes, int n_in,
                              void* d_out, int out_size, void* d_ws, size_t ws_size,
                              hipStream_t stream) {
    const float* y1      = (const float*)d_in[0];
    const float* h1_in   = (const float*)d_in[1];
    const float* c1_in   = (const float*)d_in[2];
    const float* h2_in   = (const float*)d_in[3];
    const float* c2_in   = (const float*)d_in[4];
    const float* enc_W   = (const float*)d_in[5];
    const float* gamma   = (const float*)d_in[6];
    const float* beta    = (const float*)d_in[7];
    const float* Wih1    = (const float*)d_in[8];
    const float* Whh1    = (const float*)d_in[9];
    const float* bih1    = (const float*)d_in[10];
    const float* bhh1    = (const float*)d_in[11];
    const float* Wih2    = (const float*)d_in[12];
    const float* Whh2    = (const float*)d_in[13];
    const float* bih2    = (const float*)d_in[14];
    const float* bhh2    = (const float*)d_in[15];
    const float* dense_W = (const float*)d_in[16];
    const float* dense_b = (const float*)d_in[17];
    const float* dec_W   = (const float*)d_in[18];

    float* out   = (float*)d_out;
    float* ws    = (float*)d_ws;
    float* enc_g = ws;               // 256
    float* h1_g  = ws + 256;         // 128
    float* macc  = ws + 512;         // 256*32 floats (line-padded acc + count)
    float* ph1   = ws + 8704;        // 512
    float* ph2   = ws + 9216;        // 512
    float* est_g = ws + 9728;        // 256
    unsigned* ctr  = (unsigned*)(ws + 9984);
    unsigned* flag = (unsigned*)(ws + 10016);

    k_enc <<<320, 256, 0, stream>>>(enc_W, y1, Whh1, bih1, bhh1, h1_in,
                                    Whh2, bih2, bhh2, h2_in, enc_g, ph1, ph2,
                                    macc, ctr, flag);
    k_z1  <<<128, 256, 0, stream>>>(enc_g, gamma, beta, Wih1, ph1, c1_in, h1_g, out);
    k_tail<<<264, 256, 0, stream>>>(h1_g, Wih2, ph2, c2_in, dense_W, dense_b,
                                    enc_g, dec_W, macc, est_g, ctr, flag, out);
}

// Round 12
// 18.107 us; speedup vs baseline: 3.4076x; 3.4076x over previous
//
#include <hip/hip_runtime.h>
#include <math.h>

// DTLN part-2, 4 kernels (3 boundaries = structural minimum: the dependency
// chain enc -> h1 -> h2 -> est/dec has 4 production arrows; in-kernel sync is
// ruled out empirically (grid.sync ~10us, spin-barrier ~5us, flag-poll ~30us),
// redundant panels >50KB/CU stream at ~35GB/s per CU (too slow), so each arrow
// is a kernel boundary. Cross-block fan-in only via relaxed atomicAdd with
// <=32 contributors per padded line (~0.6us, measured).
// R12 = R10 + explicit register prefetch of dec_W before the macc dependency.

#define FRAME 1024
#define ENC 256
#define HID 128
#define MSTRIDE 32  // floats between macc slots (one 128B line per row)

__device__ __forceinline__ float sigmoidf_(float x) { return 1.0f / (1.0f + __expf(-x)); }
__device__ __forceinline__ float tanhf_(float x) { return 2.0f * sigmoidf_(2.0f * x) - 1.0f; }

__device__ __forceinline__ float wred(float v) {
#pragma unroll
    for (int o = 32; o > 0; o >>= 1) v += __shfl_xor(v, o);
    return v;  // all lanes
}

// ---- K1: enc rows (256 blk) + ph1/ph2 partials (64 blk) + macc zero ----
__global__ __launch_bounds__(256) void k_enc(
    const float* __restrict__ enc_W, const float* __restrict__ y1,
    const float* __restrict__ Whh1, const float* __restrict__ bih1,
    const float* __restrict__ bhh1, const float* __restrict__ h1_in,
    const float* __restrict__ Whh2, const float* __restrict__ bih2,
    const float* __restrict__ bhh2, const float* __restrict__ h2_in,
    float* __restrict__ enc_g, float* __restrict__ ph1,
    float* __restrict__ ph2, float* __restrict__ macc) {
    const int t = threadIdx.x, lane = t & 63, w = t >> 6, bid = blockIdx.x;
    if (bid < 256) {
        const float4 a = reinterpret_cast<const float4*>(enc_W + bid * FRAME)[t];
        const float4 b = reinterpret_cast<const float4*>(y1)[t];
        float p = a.x * b.x + a.y * b.y + a.z * b.z + a.w * b.w;
        p = wred(p);
        __shared__ float red[4];
        if (lane == 0) red[w] = p;
        __syncthreads();
        if (t == 0) enc_g[bid] = red[0] + red[1] + red[2] + red[3];
    } else {
        const bool is1 = bid < 288;
        const int pb = is1 ? bid - 256 : bid - 288;   // 32 blocks each side
        const float* Whh = is1 ? Whh1 : Whh2;
        const float* bi  = is1 ? bih1 : bih2;
        const float* bh  = is1 ? bhh1 : bhh2;
        const float* hin = is1 ? h1_in : h2_in;
        float* dst       = is1 ? ph1 : ph2;
        const float2 hv = reinterpret_cast<const float2*>(hin)[lane];
#pragma unroll
        for (int j = 0; j < 4; ++j) {
            const int r = pb * 16 + w * 4 + j;        // 16 rows/block, 512 total
            const float2 a = reinterpret_cast<const float2*>(Whh + r * HID)[lane];
            float p = a.x * hv.x + a.y * hv.y;
            p = wred(p);
            if (lane == 0) dst[r] = p + bi[r] + bh[r];
        }
        if (!is1 && t < 8) macc[(pb * 8 + t) * MSTRIDE] = 0.0f;  // 32*8 = 256 slots
    }
}

// ---- K2: LN (cheap redundant) + z1 gate-rows of unit b -> h1,c1. 128 blk ----
__global__ __launch_bounds__(256) void k_z1(
    const float* __restrict__ enc_g, const float* __restrict__ gamma,
    const float* __restrict__ beta, const float* __restrict__ Wih1,
    const float* __restrict__ ph1, const float* __restrict__ c1_in,
    float* __restrict__ h1_g, float* __restrict__ out) {
    const int t = threadIdx.x, lane = t & 63, w = t >> 6, b = blockIdx.x;
    __shared__ __align__(16) float encN[ENC];
    __shared__ float red[8];
    __shared__ float zsh[4];

    const int r = b + HID * w;  // gate w of unit b
    const float4 wa = reinterpret_cast<const float4*>(Wih1 + r * ENC)[lane];
    const float ph = ph1[r];

    const float e = enc_g[t];
    const float s1 = wred(e);
    const float s2 = wred(e * e);
    if (lane == 0) { red[w] = s1; red[4 + w] = s2; }
    __syncthreads();
    const float mean = (red[0] + red[1] + red[2] + red[3]) * (1.f / ENC);
    const float var  = (red[4] + red[5] + red[6] + red[7]) * (1.f / ENC) - mean * mean;
    const float inv  = rsqrtf(var + 1e-7f);
    encN[t] = (e - mean) * inv * gamma[t] + beta[t];
    __syncthreads();

    const float4 xa = reinterpret_cast<const float4*>(encN)[lane];
    float p = wa.x * xa.x + wa.y * xa.y + wa.z * xa.z + wa.w * xa.w;
    p = wred(p);
    if (lane == 0) zsh[w] = p + ph;
    __syncthreads();
    if (t == 0) {
        const float i = sigmoidf_(zsh[0]);
        const float f = sigmoidf_(zsh[1]);
        const float g = tanhf_(zsh[2]);
        const float o = sigmoidf_(zsh[3]);
        const float c = f * c1_in[b] + i * g;
        const float h = o * tanhf_(c);
        h1_g[b] = h;
        out[FRAME + b] = h;
        out[FRAME + HID + b] = c;
    }
}

// ---- K3: z2 + gates2 for 4 units/block + rank-4 macc atomics. 32 blocks ----
__global__ __launch_bounds__(256) void k_z2(
    const float* __restrict__ h1_g, const float* __restrict__ Wih2,
    const float* __restrict__ ph2, const float* __restrict__ c2_in,
    const float* __restrict__ dense_W, float* __restrict__ macc,
    float* __restrict__ out) {
    const int t = threadIdx.x, lane = t & 63, w = t >> 6, bid = blockIdx.x;
    const int ub = bid * 4;  // 4 consecutive units per block
    __shared__ __align__(16) float hA[HID];
    __shared__ float zsh[16];   // [gate m][unit j]
    __shared__ float h2sh[4];

    // input-only loads issued first (overlap with h1_g dependency)
    const float4 dcol = *reinterpret_cast<const float4*>(dense_W + t * HID + ub);
    float2 wa[4]; float phv[4];
#pragma unroll
    for (int j = 0; j < 4; ++j) {
        const int r = (ub + j) + HID * w;   // gate w of unit ub+j
        wa[j] = reinterpret_cast<const float2*>(Wih2 + r * HID)[lane];
        phv[j] = ph2[r];
    }
    const float c2v = (t < 4) ? c2_in[ub + t] : 0.f;

    if (t < HID) hA[t] = h1_g[t];
    __syncthreads();
    const float2 xa = reinterpret_cast<const float2*>(hA)[lane];
#pragma unroll
    for (int j = 0; j < 4; ++j) {
        float p = wa[j].x * xa.x + wa[j].y * xa.y;
        p = wred(p);
        if (lane == 0) zsh[w * 4 + j] = p + phv[j];
    }
    __syncthreads();
    if (t < 4) {
        const int u = ub + t;
        const float i = sigmoidf_(zsh[0 * 4 + t]);
        const float f = sigmoidf_(zsh[1 * 4 + t]);
        const float g = tanhf_(zsh[2 * 4 + t]);
        const float o = sigmoidf_(zsh[3 * 4 + t]);
        const float c = f * c2v + i * g;
        const float h = o * tanhf_(c);
        h2sh[t] = h;
        out[FRAME + 2 * HID + u] = h;
        out[FRAME + 3 * HID + u] = c;
    }
    __syncthreads();
    // rank-4: macc[t] += dense_W[t, ub..ub+3] . h2[ub..ub+3]  (32 adds/line)
    const float contrib = dcol.x * h2sh[0] + dcol.y * h2sh[1]
                        + dcol.z * h2sh[2] + dcol.w * h2sh[3];
    atomicAdd(&macc[t * MSTRIDE], contrib);
}

// ---- K4: est finish (redundant, cheap) + dec rows. 256 blocks, 4 rows each ----
__global__ __launch_bounds__(256) void k_dec(
    const float* __restrict__ dec_W, const float* __restrict__ macc,
    const float* __restrict__ dense_b, const float* __restrict__ enc_g,
    float* __restrict__ out) {
    const int t = threadIdx.x, lane = t & 63, w = t >> 6;
    __shared__ __align__(16) float es[ENC];
    const int r = blockIdx.x * 4 + w;
    // register-prefetch dec_W FIRST: its HBM miss overlaps the macc-dependent path
    const float4 a = reinterpret_cast<const float4*>(dec_W + r * ENC)[lane];
    const float dbv = dense_b[t];
    const float egv = enc_g[t];
    const float m = macc[t * MSTRIDE];
    es[t] = sigmoidf_(m + dbv) * egv;
    __syncthreads();
    const float4 bb = reinterpret_cast<const float4*>(es)[lane];
    float p = a.x * bb.x + a.y * bb.y + a.z * bb.z + a.w * bb.w;
    p = wred(p);
    if (lane == 0) out[r] = p;
}

extern "C" void kernel_launch(void* const* d_in, const int* in_sizes, int n_in,
                              void* d_out, int out_size, void* d_ws, size_t ws_size,
                              hipStream_t stream) {
    const float* y1      = (const float*)d_in[0];
    const float* h1_in   = (const float*)d_in[1];
    const float* c1_in   = (const float*)d_in[2];
    const float* h2_in   = (const float*)d_in[3];
    const float* c2_in   = (const float*)d_in[4];
    const float* enc_W   = (const float*)d_in[5];
    const float* gamma   = (const float*)d_in[6];
    const float* beta    = (const float*)d_in[7];
    const float* Wih1    = (const float*)d_in[8];
    const float* Whh1    = (const float*)d_in[9];
    const float* bih1    = (const float*)d_in[10];
    const float* bhh1    = (const float*)d_in[11];
    const float* Wih2    = (const float*)d_in[12];
    const float* Whh2    = (const float*)d_in[13];
    const float* bih2    = (const float*)d_in[14];
    const float* bhh2    = (const float*)d_in[15];
    const float* dense_W = (const float*)d_in[16];
    const float* dense_b = (const float*)d_in[17];
    const float* dec_W   = (const float*)d_in[18];

    float* out   = (float*)d_out;
    float* ws    = (float*)d_ws;
    float* enc_g = ws;             // 256
    float* h1_g  = ws + 256;       // 128
    float* macc  = ws + 512;       // 256*32 = 8192 (line-padded)
    float* ph1   = ws + 8704;      // 512
    float* ph2   = ws + 9216;      // 512

    k_enc<<<320, 256, 0, stream>>>(enc_W, y1, Whh1, bih1, bhh1, h1_in,
                                   Whh2, bih2, bhh2, h2_in, enc_g, ph1, ph2, macc);
    k_z1 <<<128, 256, 0, stream>>>(enc_g, gamma, beta, Wih1, ph1, c1_in, h1_g, out);
    k_z2 <<<32, 256, 0, stream>>>(h1_g, Wih2, ph2, c2_in, dense_W, macc, out);
    k_dec<<<256, 256, 0, stream>>>(dec_W, macc, dense_b, enc_g, out);
}